// Round 2
// baseline (221.183 us; speedup 1.0000x reference)
//
#include <hip/hip_runtime.h>

#define BB 64
#define CC 512
#define NPIX 784
#define KK 32
#define NSA 49          // kA: 49 splits of 16 px
#define AS 800          // A row stride in shorts (784 padded to 25*32)
#define NSTEP 24        // kB full 32-wide n-steps (24*32 = 768), +1 predicated tail

typedef __attribute__((ext_vector_type(8))) short short8;
typedef __attribute__((ext_vector_type(4))) float floatx4;

__device__ __forceinline__ unsigned short f2bf(float f) {
    union { float f; unsigned u; } v; v.f = f;
    return (unsigned short)((v.u + 0x7FFFu + ((v.u >> 16) & 1u)) >> 16);
}
__device__ __forceinline__ short8 pack8(const float4& a, const float4& b) {
    short8 r;
    r[0] = (short)f2bf(a.x); r[1] = (short)f2bf(a.y);
    r[2] = (short)f2bf(a.z); r[3] = (short)f2bf(a.w);
    r[4] = (short)f2bf(b.x); r[5] = (short)f2bf(b.y);
    r[6] = (short)f2bf(b.z); r[7] = (short)f2bf(b.w);
    return r;
}

// ---------------------------------------------------------------------------
// kA: per (16-px tile, batch): A[k][px] = softmax_k(scale_k*(xsq+csq_k-2 x.c_k))
//  - 4 waves split the C=512 contraction (4 kc-steps of 32 each), partial MFMA
//    accumulators reduced via LDS; wave 0 runs softmax epilogue.
//  - cw fragments read direct from global (L1/L2-hot, 64 KB total).
//  - A written to workspace as bf16 [b][k][n], n padded to 800 with zeros.
// ---------------------------------------------------------------------------
__global__ __launch_bounds__(256) void kA(const float* __restrict__ x,
                                          const float* __restrict__ cw,
                                          const float* __restrict__ scale,
                                          unsigned short* __restrict__ Ag)
{
    __shared__ __align__(16) float red[4][64][12];   // acc0[4], acc1[4], xsq
    __shared__ float csq_p[8][KK];
    __shared__ float csq_l[KK];

    const int t    = threadIdx.x;
    const int lane = t & 63, w = t >> 6;
    const int col  = lane & 15, quad = lane >> 4;
    const int split = blockIdx.x, b = blockIdx.y;
    const int p0    = split * 16;

    // ---- csq partials (fp32, from fp32 cw) ----
    {
        const int k = t & 31, part = t >> 5;
        const float* cp = cw + k * CC + part * 64;
        float s = 0.f;
#pragma unroll
        for (int i = 0; i < 16; ++i) {
            const float4 v = *(const float4*)&cp[i * 4];
            s += v.x * v.x + v.y * v.y + v.z * v.z + v.w * v.w;
        }
        csq_p[part][k] = s;
    }

    // ---- main MFMA: wave w covers kc = 4w .. 4w+3 (c in [w*128, w*128+128)) ----
    const float* xb = x + (size_t)b * CC * NPIX + p0 + col;
    floatx4 acc0 = {0.f, 0.f, 0.f, 0.f};
    floatx4 acc1 = {0.f, 0.f, 0.f, 0.f};
    float xsqp = 0.f;
#pragma unroll
    for (int i = 0; i < 4; ++i) {
        const int c0 = (w * 4 + i) * 32 + quad * 8;
        float va[8];
#pragma unroll
        for (int j = 0; j < 8; ++j) va[j] = xb[(size_t)(c0 + j) * NPIX];
        const float4 c0a = *(const float4*)&cw[col * CC + c0];
        const float4 c0b = *(const float4*)&cw[col * CC + c0 + 4];
        const float4 c1a = *(const float4*)&cw[(col + 16) * CC + c0];
        const float4 c1b = *(const float4*)&cw[(col + 16) * CC + c0 + 4];
        short8 a;
#pragma unroll
        for (int j = 0; j < 8; ++j) { xsqp += va[j] * va[j]; a[j] = (short)f2bf(va[j]); }
        acc0 = __builtin_amdgcn_mfma_f32_16x16x32_bf16(a, pack8(c0a, c0b), acc0, 0, 0, 0);
        acc1 = __builtin_amdgcn_mfma_f32_16x16x32_bf16(a, pack8(c1a, c1b), acc1, 0, 0, 0);
    }
    *(floatx4*)&red[w][lane][0] = acc0;
    *(floatx4*)&red[w][lane][4] = acc1;
    red[w][lane][8] = xsqp;
    __syncthreads();
    if (t < KK) {
        float s = 0.f;
#pragma unroll
        for (int p = 0; p < 8; ++p) s += csq_p[p][t];
        csq_l[t] = s;
    }
    __syncthreads();

    if (w == 0) {
        // cross-wave reduction of partial accumulators + xsq
        floatx4 A0 = *(const floatx4*)&red[0][lane][0];
        floatx4 A1 = *(const floatx4*)&red[0][lane][4];
        float xq = red[0][lane][8];
#pragma unroll
        for (int wv = 1; wv < 4; ++wv) {
            A0 += *(const floatx4*)&red[wv][lane][0];
            A1 += *(const floatx4*)&red[wv][lane][4];
            xq += red[wv][lane][8];
        }
        xq += __shfl_xor(xq, 16);
        xq += __shfl_xor(xq, 32);
        const float s0 = scale[col], s1 = scale[col + 16];
        const float q0 = csq_l[col], q1 = csq_l[col + 16];
        unsigned short* Ab = Ag + (size_t)b * KK * AS + p0;
#pragma unroll
        for (int r = 0; r < 4; ++r) {
            const float xqr = __shfl(xq, quad * 4 + r);   // lane (quad*4+r) holds that px's xsq
            const float d0 = s0 * (xqr + q0 - 2.f * A0[r]);
            const float d1 = s1 * (xqr + q1 - 2.f * A1[r]);
            float mx = fmaxf(d0, d1);
            mx = fmaxf(mx, __shfl_xor(mx, 1));
            mx = fmaxf(mx, __shfl_xor(mx, 2));
            mx = fmaxf(mx, __shfl_xor(mx, 4));
            mx = fmaxf(mx, __shfl_xor(mx, 8));
            const float e0 = __expf(d0 - mx), e1 = __expf(d1 - mx);
            float sm = e0 + e1;
            sm += __shfl_xor(sm, 1);
            sm += __shfl_xor(sm, 2);
            sm += __shfl_xor(sm, 4);
            sm += __shfl_xor(sm, 8);
            const float inv = 1.f / sm;
            Ab[col * AS + quad * 4 + r]        = f2bf(e0 * inv);
            Ab[(col + 16) * AS + quad * 4 + r] = f2bf(e1 * inv);
        }
    } else if (w == 1 && split == NSA - 1) {
        // zero A pad region n in [784, 800): 32 rows x 16 shorts
        const short8 z = {0, 0, 0, 0, 0, 0, 0, 0};
        const int k = lane >> 1, off = (lane & 1) * 8;
        *(short8*)&Ag[(size_t)b * KK * AS + (size_t)k * AS + NPIX + off] = z;
    }
}

// ---------------------------------------------------------------------------
// kB: per (c-chunk of 64, batch): out[k][c] = sum_n A[k][n] x[c][n] - wsum_k cw[k][c]
//  - barrier-free main loop, A (L2-hot) and x (L3-hot from kA) direct from global
//  - wsum recomputed per block from A (issued early, latency hidden)
// ---------------------------------------------------------------------------
__global__ __launch_bounds__(256) void kB(const float* __restrict__ x,
                                          const float* __restrict__ cw,
                                          const unsigned short* __restrict__ Ag,
                                          float* __restrict__ out)
{
    __shared__ float wred[KK][8];
    __shared__ float wsum_l[KK];

    const int t    = threadIdx.x;
    const int lane = t & 63, w = t >> 6;
    const int col  = lane & 15, quad = lane >> 4;
    const int cch  = blockIdx.x, b = blockIdx.y;

    const unsigned short* Ab = Ag + (size_t)b * KK * AS;

    // ---- wsum partials: k = t&31, 98 n-values per thread (49 dwords = 2 bf16 each) ----
    {
        const int k = t & 31, part = t >> 5;
        const unsigned* ap = (const unsigned*)(Ab + (size_t)k * AS) + part * 49;
        float s = 0.f;
#pragma unroll
        for (int i = 0; i < 49; ++i) {
            const unsigned u = ap[i];
            union { unsigned uu; float f; } lo, hi;
            lo.uu = u << 16; hi.uu = u & 0xffff0000u;
            s += lo.f + hi.f;
        }
        wred[k][part] = s;
    }

    // ---- main GEMM: this wave owns 16 c-rows; contract n = 0..800 ----
    const int c = cch * 64 + w * 16 + col;
    const float* xp = x + ((size_t)b * CC + c) * NPIX;
    const unsigned short* a0p = Ab + (size_t)col * AS;
    const unsigned short* a1p = Ab + (size_t)(col + 16) * AS;
    const int qo = quad * 8;

    floatx4 acc0 = {0.f, 0.f, 0.f, 0.f};
    floatx4 acc1 = {0.f, 0.f, 0.f, 0.f};
#pragma unroll 6
    for (int s = 0; s < NSTEP; ++s) {
        const int off = s * 32 + qo;
        const short8 av0 = *(const short8*)&a0p[off];
        const short8 av1 = *(const short8*)&a1p[off];
        const float4 xv0 = *(const float4*)&xp[off];
        const float4 xv1 = *(const float4*)&xp[off + 4];
        const short8 bv = pack8(xv0, xv1);
        acc0 = __builtin_amdgcn_mfma_f32_16x16x32_bf16(av0, bv, acc0, 0, 0, 0);
        acc1 = __builtin_amdgcn_mfma_f32_16x16x32_bf16(av1, bv, acc1, 0, 0, 0);
    }
    {   // tail step: n in [768,800); x rows end at 784 -> predicate quads 2,3 (A pad is zero)
        const int off = NSTEP * 32 + qo;
        const short8 av0 = *(const short8*)&a0p[off];
        const short8 av1 = *(const short8*)&a1p[off];
        float4 xv0 = make_float4(0.f, 0.f, 0.f, 0.f);
        float4 xv1 = make_float4(0.f, 0.f, 0.f, 0.f);
        if (quad < 2) {
            xv0 = *(const float4*)&xp[off];
            xv1 = *(const float4*)&xp[off + 4];
        }
        const short8 bv = pack8(xv0, xv1);
        acc0 = __builtin_amdgcn_mfma_f32_16x16x32_bf16(av0, bv, acc0, 0, 0, 0);
        acc1 = __builtin_amdgcn_mfma_f32_16x16x32_bf16(av1, bv, acc1, 0, 0, 0);
    }

    __syncthreads();
    if (t < KK) {
        float s = 0.f;
#pragma unroll
        for (int p = 0; p < 8; ++p) s += wred[t][p];
        wsum_l[t] = s;
    }
    __syncthreads();

    // ---- fused epilogue: out = W - wsum*cw ----
    float* ob = out + (size_t)b * KK * CC + c;
    const float* cp = cw + c;
#pragma unroll
    for (int r = 0; r < 4; ++r) {
        const int k0 = quad * 4 + r;
        ob[(size_t)k0 * CC]        = acc0[r] - wsum_l[k0]      * cp[(size_t)k0 * CC];
        ob[(size_t)(k0 + 16) * CC] = acc1[r] - wsum_l[k0 + 16] * cp[(size_t)(k0 + 16) * CC];
    }
}

extern "C" void kernel_launch(void* const* d_in, const int* in_sizes, int n_in,
                              void* d_out, int out_size, void* d_ws, size_t ws_size,
                              hipStream_t stream) {
    const float* x     = (const float*)d_in[0];   // (64, 512, 28, 28)
    const float* cw    = (const float*)d_in[1];   // (32, 512)
    const float* scale = (const float*)d_in[2];   // (32,)
    float* out = (float*)d_out;                   // (64, 32, 512)
    unsigned short* Ag = (unsigned short*)d_ws;   // bf16 A [64][32][800] = 3.28 MB

    kA<<<dim3(NSA, BB), dim3(256), 0, stream>>>(x, cw, scale, Ag);
    kB<<<dim3(8, BB), dim3(256), 0, stream>>>(x, cw, Ag, out);
}

// Round 3
// 182.779 us; speedup vs baseline: 1.2101x; 1.2101x over previous
//
#include <hip/hip_runtime.h>

#define BB 64
#define CC 512
#define NPIX 784
#define KK 32
#define NSA 13          // kA: 13 splits of 64 px (split 12 overlaps: p0=720)
#define AS 800          // A row stride in shorts (784 padded to 25*32)
#define CW_S 520        // cw LDS row stride (shorts): 260 dw == 4 mod 32 -> conflict-free b128
#define NSTEP 24        // kB full 32-wide n-steps (24*32 = 768), +1 predicated tail

typedef __attribute__((ext_vector_type(8))) short short8;
typedef __attribute__((ext_vector_type(4))) float floatx4;
typedef __attribute__((ext_vector_type(4))) unsigned short ushort4v;

// workspace layout: A bf16 [64][32][800] (3.28 MB), then wsum_p fp32 [13][64][32]
#define WSUM_OFF (BB * KK * AS)   // in shorts; byte offset 6553600 (16-aligned)

__device__ __forceinline__ unsigned short f2bf(float f) {
    union { float f; unsigned u; } v; v.f = f;
    return (unsigned short)((v.u + 0x7FFFu + ((v.u >> 16) & 1u)) >> 16);
}
__device__ __forceinline__ float bf2f(unsigned short h) {
    union { unsigned u; float f; } v; v.u = ((unsigned)h) << 16; return v.f;
}
__device__ __forceinline__ short8 pack8(const float4& a, const float4& b) {
    short8 r;
    r[0] = (short)f2bf(a.x); r[1] = (short)f2bf(a.y);
    r[2] = (short)f2bf(a.z); r[3] = (short)f2bf(a.w);
    r[4] = (short)f2bf(b.x); r[5] = (short)f2bf(b.y);
    r[6] = (short)f2bf(b.z); r[7] = (short)f2bf(b.w);
    return r;
}

// ---------------------------------------------------------------------------
// kA: per (64-px split, batch): A[k][px] = softmax_k(scale_k*(xsq+csq_k-2 x.c_k))
//  - one 16-px MFMA tile per wave, FULL C=512 contraction per wave:
//    16 kc-steps, register double-buffered strided x loads (proven 2.2+ TB/s
//    pattern from the round-0 kernel; deep per-wave memory pipeline).
//  - cw staged once to LDS bf16 (CW_S=520: conflict-free b128 reads).
//  - A written bf16 to ws [b][k][n]; per-split wsum partials also written.
// ---------------------------------------------------------------------------
__global__ __launch_bounds__(256, 4) void kA(const float* __restrict__ x,
                                             const float* __restrict__ cw,
                                             const float* __restrict__ scale,
                                             unsigned short* __restrict__ Ag)
{
    __shared__ __align__(16) unsigned short cs[KK * CW_S];   // 33280 B
    __shared__ float csq_p[8][KK];
    __shared__ float csq_l[KK];
    __shared__ float wredA[4][KK];

    const int t    = threadIdx.x;
    const int lane = t & 63, w = t >> 6;
    const int col  = lane & 15, quad = lane >> 4;
    const int split = blockIdx.x, b = blockIdx.y;
    const int p0    = (split < 12) ? split * 64 : 720;   // split 12 overlaps by 48 px

    // ---- zero A pad region n in [784,800) once per batch (idempotent) ----
    if (split == 0 && t < 64) {
        const short8 z = {0, 0, 0, 0, 0, 0, 0, 0};
        const int k = t >> 1, off = (t & 1) * 8;
        *(short8*)&Ag[(size_t)b * KK * AS + (size_t)k * AS + NPIX + off] = z;
    }

    // ---- stage cw -> bf16 LDS ----
#pragma unroll 4
    for (int j = 0; j < 16; ++j) {
        const int qidx = t + j * 256;
        const int row = qidx >> 7, qc = qidx & 127;
        const float4 v = *(const float4*)&cw[row * CC + qc * 4];
        ushort4v p; p.x = f2bf(v.x); p.y = f2bf(v.y); p.z = f2bf(v.z); p.w = f2bf(v.w);
        *(ushort4v*)&cs[row * CW_S + qc * 4] = p;
    }
    __syncthreads();
    // ---- csq ----
    {
        const int k = t & 31, part = t >> 5;
        float s = 0.f;
        for (int i = 0; i < 64; ++i) {
            const float v = bf2f(cs[k * CW_S + part * 64 + i]);
            s += v * v;
        }
        csq_p[part][k] = s;
    }
    __syncthreads();
    if (t < KK) {
        float s = 0.f;
#pragma unroll
        for (int p = 0; p < 8; ++p) s += csq_p[p][t];
        csq_l[t] = s;
    }
    __syncthreads();

    const float s0 = scale[col], s1 = scale[col + 16];
    const float q0 = csq_l[col], q1 = csq_l[col + 16];

    // ---- main MFMA: wave w owns px-tile [p0 + w*16, +16), contracts all C ----
    const int px = p0 + w * 16 + col;
    const float* xb = x + (size_t)b * CC * NPIX + px;

    floatx4 acc0 = {0.f, 0.f, 0.f, 0.f};
    floatx4 acc1 = {0.f, 0.f, 0.f, 0.f};
    float xsqp = 0.f;
    float va[8], vb[8];

#pragma unroll
    for (int j = 0; j < 8; ++j) va[j] = xb[(size_t)(quad * 8 + j) * NPIX];

#pragma unroll
    for (int kc = 0; kc < 16; kc += 2) {
        // prefetch kc+1 into vb
        {
            const int cb = (kc + 1) * 32 + quad * 8;
#pragma unroll
            for (int j = 0; j < 8; ++j) vb[j] = xb[(size_t)(cb + j) * NPIX];
        }
        // process va (kc)
        {
#pragma unroll
            for (int j = 0; j < 8; ++j) xsqp += va[j] * va[j];
            short8 a;
#pragma unroll
            for (int j = 0; j < 8; ++j) a[j] = (short)f2bf(va[j]);
            const int cb0 = kc * 32 + quad * 8;
            const short8 b0 = *(const short8*)&cs[col * CW_S + cb0];
            const short8 b1 = *(const short8*)&cs[(col + 16) * CW_S + cb0];
            acc0 = __builtin_amdgcn_mfma_f32_16x16x32_bf16(a, b0, acc0, 0, 0, 0);
            acc1 = __builtin_amdgcn_mfma_f32_16x16x32_bf16(a, b1, acc1, 0, 0, 0);
        }
        // prefetch kc+2 into va
        if (kc + 2 < 16) {
            const int cb = (kc + 2) * 32 + quad * 8;
#pragma unroll
            for (int j = 0; j < 8; ++j) va[j] = xb[(size_t)(cb + j) * NPIX];
        }
        // process vb (kc+1)
        {
#pragma unroll
            for (int j = 0; j < 8; ++j) xsqp += vb[j] * vb[j];
            short8 a;
#pragma unroll
            for (int j = 0; j < 8; ++j) a[j] = (short)f2bf(vb[j]);
            const int cb1 = (kc + 1) * 32 + quad * 8;
            const short8 b0 = *(const short8*)&cs[col * CW_S + cb1];
            const short8 b1 = *(const short8*)&cs[(col + 16) * CW_S + cb1];
            acc0 = __builtin_amdgcn_mfma_f32_16x16x32_bf16(a, b0, acc0, 0, 0, 0);
            acc1 = __builtin_amdgcn_mfma_f32_16x16x32_bf16(a, b1, acc1, 0, 0, 0);
        }
    }

    // xsq: sum quad slices -> every lane has xsq for its col's px
    xsqp += __shfl_xor(xsqp, 16);
    xsqp += __shfl_xor(xsqp, 32);

    // fused softmax epilogue; D row = px = quad*4+r, col = k
    unsigned short* Ab = Ag + (size_t)b * KK * AS + p0 + w * 16;
    float ts0 = 0.f, ts1 = 0.f;   // per-lane partial wsum over this tile
#pragma unroll
    for (int r = 0; r < 4; ++r) {
        const float xq = __shfl(xsqp, quad * 4 + r);   // lane (quad*4+r) holds that px's xsq
        const float d0 = s0 * (xq + q0 - 2.f * acc0[r]);
        const float d1 = s1 * (xq + q1 - 2.f * acc1[r]);
        float mx = fmaxf(d0, d1);
        mx = fmaxf(mx, __shfl_xor(mx, 1));
        mx = fmaxf(mx, __shfl_xor(mx, 2));
        mx = fmaxf(mx, __shfl_xor(mx, 4));
        mx = fmaxf(mx, __shfl_xor(mx, 8));
        const float e0 = __expf(d0 - mx), e1 = __expf(d1 - mx);
        float sm = e0 + e1;
        sm += __shfl_xor(sm, 1);
        sm += __shfl_xor(sm, 2);
        sm += __shfl_xor(sm, 4);
        sm += __shfl_xor(sm, 8);
        const float inv = 1.f / sm;
        const float a0 = e0 * inv, a1 = e1 * inv;
        Ab[col * AS + quad * 4 + r]        = f2bf(a0);
        Ab[(col + 16) * AS + quad * 4 + r] = f2bf(a1);
        ts0 += a0; ts1 += a1;
    }

    // per-tile wsum: reduce over the 4 quads (16 px of this tile)
    ts0 += __shfl_xor(ts0, 16); ts0 += __shfl_xor(ts0, 32);
    ts1 += __shfl_xor(ts1, 16); ts1 += __shfl_xor(ts1, 32);
    if (quad == 0) { wredA[w][col] = ts0; wredA[w][col + 16] = ts1; }
    __syncthreads();
    if (t < KK) {
        // split 12: tiles w=0..2 duplicate split 11's coverage -> count only w=3
        float s;
        if (split < 12) s = wredA[0][t] + wredA[1][t] + wredA[2][t] + wredA[3][t];
        else            s = wredA[3][t];
        float* wsf = (float*)(Ag + WSUM_OFF);
        wsf[(size_t)(split * BB + b) * KK + t] = s;
    }
}

// ---------------------------------------------------------------------------
// kB: per (c-chunk of 64, batch): out[k][c] = sum_n A[k][n] x[c][n] - wsum_k cw[k][c]
//  - barrier-free main loop, A (L2-hot) and x (L3-hot from kA) direct from global
//  - wsum from kA's per-split partials (13 adds per k)
// ---------------------------------------------------------------------------
__global__ __launch_bounds__(256) void kB(const float* __restrict__ x,
                                          const float* __restrict__ cw,
                                          const unsigned short* __restrict__ Ag,
                                          float* __restrict__ out)
{
    __shared__ float wsum_l[KK];

    const int t    = threadIdx.x;
    const int lane = t & 63, w = t >> 6;
    const int col  = lane & 15, quad = lane >> 4;
    const int cch  = blockIdx.x, b = blockIdx.y;

    const unsigned short* Ab = Ag + (size_t)b * KK * AS;

    // ---- wsum: sum kA's 13 per-split partials ----
    if (t < KK) {
        const float* wsf = (const float*)(Ag + WSUM_OFF);
        float s = 0.f;
#pragma unroll
        for (int sp = 0; sp < NSA; ++sp) s += wsf[(size_t)(sp * BB + b) * KK + t];
        wsum_l[t] = s;
    }

    // ---- main GEMM: this wave owns 16 c-rows; contract n = 0..800 ----
    const int c = cch * 64 + w * 16 + col;
    const float* xp = x + ((size_t)b * CC + c) * NPIX;
    const unsigned short* a0p = Ab + (size_t)col * AS;
    const unsigned short* a1p = Ab + (size_t)(col + 16) * AS;
    const int qo = quad * 8;

    floatx4 acc0 = {0.f, 0.f, 0.f, 0.f};
    floatx4 acc1 = {0.f, 0.f, 0.f, 0.f};
#pragma unroll 6
    for (int s = 0; s < NSTEP; ++s) {
        const int off = s * 32 + qo;
        const short8 av0 = *(const short8*)&a0p[off];
        const short8 av1 = *(const short8*)&a1p[off];
        const float4 xv0 = *(const float4*)&xp[off];
        const float4 xv1 = *(const float4*)&xp[off + 4];
        const short8 bv = pack8(xv0, xv1);
        acc0 = __builtin_amdgcn_mfma_f32_16x16x32_bf16(av0, bv, acc0, 0, 0, 0);
        acc1 = __builtin_amdgcn_mfma_f32_16x16x32_bf16(av1, bv, acc1, 0, 0, 0);
    }
    {   // tail step: n in [768,800); x rows end at 784 -> predicate quads 2,3 (A pad is zero)
        const int off = NSTEP * 32 + qo;
        const short8 av0 = *(const short8*)&a0p[off];
        const short8 av1 = *(const short8*)&a1p[off];
        float4 xv0 = make_float4(0.f, 0.f, 0.f, 0.f);
        float4 xv1 = make_float4(0.f, 0.f, 0.f, 0.f);
        if (quad < 2) {
            xv0 = *(const float4*)&xp[off];
            xv1 = *(const float4*)&xp[off + 4];
        }
        const short8 bv = pack8(xv0, xv1);
        acc0 = __builtin_amdgcn_mfma_f32_16x16x32_bf16(av0, bv, acc0, 0, 0, 0);
        acc1 = __builtin_amdgcn_mfma_f32_16x16x32_bf16(av1, bv, acc1, 0, 0, 0);
    }

    __syncthreads();   // wsum_l ready

    // ---- fused epilogue: out = W - wsum*cw ----
    float* ob = out + (size_t)b * KK * CC + c;
    const float* cp = cw + c;
#pragma unroll
    for (int r = 0; r < 4; ++r) {
        const int k0 = quad * 4 + r;
        ob[(size_t)k0 * CC]        = acc0[r] - wsum_l[k0]      * cp[(size_t)k0 * CC];
        ob[(size_t)(k0 + 16) * CC] = acc1[r] - wsum_l[k0 + 16] * cp[(size_t)(k0 + 16) * CC];
    }
}

extern "C" void kernel_launch(void* const* d_in, const int* in_sizes, int n_in,
                              void* d_out, int out_size, void* d_ws, size_t ws_size,
                              hipStream_t stream) {
    const float* x     = (const float*)d_in[0];   // (64, 512, 28, 28)
    const float* cw    = (const float*)d_in[1];   // (32, 512)
    const float* scale = (const float*)d_in[2];   // (32,)
    float* out = (float*)d_out;                   // (64, 32, 512)
    unsigned short* Ag = (unsigned short*)d_ws;   // A bf16 [64][32][800] + wsum_p f32 [13][64][32]

    kA<<<dim3(NSA, BB), dim3(256), 0, stream>>>(x, cw, scale, Ag);
    kB<<<dim3(8, BB), dim3(256), 0, stream>>>(x, cw, Ag, out);
}